// Round 4
// baseline (116.714 us; speedup 1.0000x reference)
//
#include <hip/hip_runtime.h>

#define LAMBDA_NOOBJ 0.5f
#define LAMBDA_COORD 5.0f

// Private-cell layout: each thread owns GROUP=4 whole cells (20 floats = 80B
// per stream) -> no cross-lane conf sharing at all. Depth-2 interleave: all
// 20 float4 loads (2 groups x 2 streams x 5) are issued before consumption,
// with independent accumulators, to maximize memory-level parallelism.
// __launch_bounds__(256,4) caps VGPR at 128 so the compiler keeps them live.

__device__ __forceinline__ void group_accum(const float4* __restrict__ p4,
                                            const float4* __restrict__ t4,
                                            float& box, float& obj, float& noobj) {
  float p[20], t[20];
#pragma unroll
  for (int i = 0; i < 5; ++i) {
    float4 a = p4[i];
    float4 b = t4[i];
    p[i * 4 + 0] = a.x; p[i * 4 + 1] = a.y; p[i * 4 + 2] = a.z; p[i * 4 + 3] = a.w;
    t[i * 4 + 0] = b.x; t[i * 4 + 1] = b.y; t[i * 4 + 2] = b.z; t[i * 4 + 3] = b.w;
  }
#pragma unroll
  for (int c = 0; c < 4; ++c) {
    float c_t = t[c * 5];
    float cd = c_t - p[c * 5];
    cd *= cd;
    float bd = 0.f;
#pragma unroll
    for (int k = 1; k < 5; ++k) {
      float d = t[c * 5 + k] - p[c * 5 + k];
      bd += d * d;
    }
    bool is_obj = (c_t == 1.0f);
    box += is_obj ? bd : 0.f;
    obj += is_obj ? cd : 0.f;
    noobj += is_obj ? 0.f : cd;
  }
}

__global__ __launch_bounds__(256, 4) void yolo_loss_kernel(
    const float4* __restrict__ pred4,
    const float4* __restrict__ targ4,
    const float* __restrict__ pred,
    const float* __restrict__ targ,
    float* __restrict__ out,   // out[1]=box, out[2]=obj, out[3]=noobj
    int ngroups, int ncells) {
  const int tid = blockIdx.x * blockDim.x + threadIdx.x;
  const int stride = gridDim.x * blockDim.x;

  float boxA = 0.f, objA = 0.f, noobjA = 0.f;
  float boxB = 0.f, objB = 0.f, noobjB = 0.f;

  int g = tid;
  // Depth-2: two groups per iteration; all 20 loads issued before compute.
  for (; g + stride < ngroups; g += 2 * stride) {
    const float4* pA = pred4 + (size_t)g * 5;
    const float4* tA = targ4 + (size_t)g * 5;
    const float4* pB = pred4 + (size_t)(g + stride) * 5;
    const float4* tB = targ4 + (size_t)(g + stride) * 5;
    float4 la0 = pA[0], la1 = pA[1], la2 = pA[2], la3 = pA[3], la4 = pA[4];
    float4 ma0 = tA[0], ma1 = tA[1], ma2 = tA[2], ma3 = tA[3], ma4 = tA[4];
    float4 lb0 = pB[0], lb1 = pB[1], lb2 = pB[2], lb3 = pB[3], lb4 = pB[4];
    float4 mb0 = tB[0], mb1 = tB[1], mb2 = tB[2], mb3 = tB[3], mb4 = tB[4];
    float4 pa[5] = {la0, la1, la2, la3, la4};
    float4 ta[5] = {ma0, ma1, ma2, ma3, ma4};
    float4 pb[5] = {lb0, lb1, lb2, lb3, lb4};
    float4 tb[5] = {mb0, mb1, mb2, mb3, mb4};
    group_accum(pa, ta, boxA, objA, noobjA);
    group_accum(pb, tb, boxB, objB, noobjB);
  }
  // Fixup: remaining single groups.
  for (; g < ngroups; g += stride) {
    const float4* pA = pred4 + (size_t)g * 5;
    const float4* tA = targ4 + (size_t)g * 5;
    float4 pa[5] = {pA[0], pA[1], pA[2], pA[3], pA[4]};
    float4 ta[5] = {tA[0], tA[1], tA[2], tA[3], tA[4]};
    group_accum(pa, ta, boxA, objA, noobjA);
  }

  float box = boxA + boxB, obj = objA + objB, noobj = noobjA + noobjB;

  // Tail cells (ncells % 4 != 0) — not hit for this size, kept for generality.
  for (int c = ngroups * 4 + tid; c < ncells; c += stride) {
    const float* pc = pred + (size_t)c * 5;
    const float* tc = targ + (size_t)c * 5;
    float c_t = tc[0];
    float cd = c_t - pc[0];
    cd *= cd;
    float bd = 0.f;
#pragma unroll
    for (int k = 1; k < 5; ++k) {
      float d = tc[k] - pc[k];
      bd += d * d;
    }
    bool is_obj = (c_t == 1.0f);
    box += is_obj ? bd : 0.f;
    obj += is_obj ? cd : 0.f;
    noobj += is_obj ? 0.f : cd;
  }

  // Wave (64-lane) reduction.
#pragma unroll
  for (int off = 32; off > 0; off >>= 1) {
    box   += __shfl_down(box, off);
    obj   += __shfl_down(obj, off);
    noobj += __shfl_down(noobj, off);
  }

  __shared__ float s[3][4];
  const int lane = threadIdx.x & 63;
  const int wid = threadIdx.x >> 6;
  if (lane == 0) {
    s[0][wid] = box;
    s[1][wid] = obj;
    s[2][wid] = noobj;
  }
  __syncthreads();
  if (threadIdx.x == 0) {
    float b = s[0][0] + s[0][1] + s[0][2] + s[0][3];
    float o = s[1][0] + s[1][1] + s[1][2] + s[1][3];
    float n = s[2][0] + s[2][1] + s[2][2] + s[2][3];
    atomicAdd(&out[1], LAMBDA_COORD * b);
    atomicAdd(&out[2], o);
    atomicAdd(&out[3], LAMBDA_NOOBJ * n);
  }
}

__global__ void yolo_loss_finalize(float* __restrict__ out) {
  out[0] = out[1] + out[2] + out[3];
}

extern "C" void kernel_launch(void* const* d_in, const int* in_sizes, int n_in,
                              void* d_out, int out_size, void* d_ws, size_t ws_size,
                              hipStream_t stream) {
  const float* pred = (const float*)d_in[0];
  const float* targ = (const float*)d_in[1];
  float* out = (float*)d_out;

  const int ncells = in_sizes[0] / 5;   // 6,553,600
  const int ngroups = ncells / 4;       // 1,638,400

  // d_out is poisoned once and never re-zeroed between replays; the kernel
  // accumulates with atomics, so zero it ourselves every call.
  hipMemsetAsync(d_out, 0, out_size * sizeof(float), stream);

  const int block = 256;
  const int grid = 2048;  // 8 blocks/CU
  yolo_loss_kernel<<<grid, block, 0, stream>>>(
      (const float4*)pred, (const float4*)targ, pred, targ, out, ngroups, ncells);
  yolo_loss_finalize<<<1, 1, 0, stream>>>(out);
}